// Round 3
// baseline (192.482 us; speedup 1.0000x reference)
//
#include <hip/hip_runtime.h>

static constexpr int N = 4096;
static constexpr int D = 8192;
static constexpr int BLOCK = 256;           // 4 waves = 4 rows per block
static constexpr int ROWS_PER_BLOCK = 4;

// One wave per row: no barriers, no LDS, wave-shuffle reduction only.
__global__ __launch_bounds__(BLOCK) void supcon_rows(
    const float* __restrict__ emb,
    const int* __restrict__ labels,
    float* __restrict__ row_out)
{
    const int wave = threadIdx.x >> 6;
    const int lane = threadIdx.x & 63;
    const int row  = blockIdx.x * ROWS_PER_BLOCK + wave;
    const int lab_i = labels[row];          // wave-uniform -> scalar load

    const float4* rowp = reinterpret_cast<const float4*>(emb + (size_t)row * D);
    const int4*   labp = reinterpret_cast<const int4*>(labels);

    float denom = 0.f, ssum = 0.f, diag = 0.f, fcnt = 0.f;

    // Phase 1: j in [0, N) -> denom + masked B-sum + count + diagonal.
    // 1024 float4 across 64 lanes = 16 iters; 2 chunks of 8 (16 loads in flight).
    #pragma unroll
    for (int c = 0; c < 2; ++c) {
        float4 v[8]; int4 lj[8];
        #pragma unroll
        for (int i = 0; i < 8; ++i) {
            const int idx = (c * 8 + i) * 64 + lane;
            v[i]  = rowp[idx];
            lj[i] = labp[idx];              // same addrs in all 4 waves -> L1 hit
        }
        #pragma unroll
        for (int i = 0; i < 8; ++i) {
            const int j0 = ((c * 8 + i) * 64 + lane) * 4;
            const float xs[4] = {v[i].x, v[i].y, v[i].z, v[i].w};
            const int   ls[4] = {lj[i].x, lj[i].y, lj[i].z, lj[i].w};
            #pragma unroll
            for (int k = 0; k < 4; ++k) {
                float a = __expf(xs[k] * xs[k] * 0.1f);
                denom += a;
                float b = __expf(a * 0.1f);               // unconditional: no divergence
                bool match = (ls[k] == lab_i) && (j0 + k != row);
                ssum += match ? b : 0.f;
                fcnt += match ? 1.f : 0.f;
                diag += (j0 + k == row) ? a : 0.f;        // exactly one lane/row
            }
        }
    }

    // Phase 2: j in [N, D) -> denom only. float4 idx 1024..2047.
    #pragma unroll
    for (int c = 0; c < 2; ++c) {
        float4 v[8];
        #pragma unroll
        for (int i = 0; i < 8; ++i)
            v[i] = rowp[1024 + (c * 8 + i) * 64 + lane];
        #pragma unroll
        for (int i = 0; i < 8; ++i) {
            denom += __expf(v[i].x * v[i].x * 0.1f);
            denom += __expf(v[i].y * v[i].y * 0.1f);
            denom += __expf(v[i].z * v[i].z * 0.1f);
            denom += __expf(v[i].w * v[i].w * 0.1f);
        }
    }

    // wave-64 shuffle reduction (the only reduction needed)
    #pragma unroll
    for (int off = 32; off > 0; off >>= 1) {
        denom += __shfl_down(denom, off);
        ssum  += __shfl_down(ssum,  off);
        diag  += __shfl_down(diag,  off);
        fcnt  += __shfl_down(fcnt,  off);
    }
    if (lane == 0) {
        const float dn = denom - diag;      // denom_i = sum_d A[i,d] - A[i,i]
        row_out[row] = __logf(ssum) - __logf(dn) - __logf(fcnt);
    }
}

// 4096 row values -> scalar, one block of 1024 threads
__global__ __launch_bounds__(1024) void reduce_rows(
    const float* __restrict__ row_vals, float* __restrict__ out)
{
    const int tid = threadIdx.x;
    float4 x = reinterpret_cast<const float4*>(row_vals)[tid];
    float s = x.x + x.y + x.z + x.w;
    #pragma unroll
    for (int off = 32; off > 0; off >>= 1)
        s += __shfl_down(s, off);
    __shared__ float sb[16];
    if ((tid & 63) == 0) sb[tid >> 6] = s;
    __syncthreads();
    if (tid == 0) {
        float t = 0.f;
        #pragma unroll
        for (int w = 0; w < 16; ++w) t += sb[w];
        *out = t;
    }
}

extern "C" void kernel_launch(void* const* d_in, const int* in_sizes, int n_in,
                              void* d_out, int out_size, void* d_ws, size_t ws_size,
                              hipStream_t stream) {
    const float* emb  = (const float*)d_in[0];
    const int* labels = (const int*)d_in[1];
    float* out        = (float*)d_out;
    float* row_vals   = (float*)d_ws;   // 4096 floats = 16 KB scratch

    supcon_rows<<<dim3(N / ROWS_PER_BLOCK), dim3(BLOCK), 0, stream>>>(emb, labels, row_vals);
    reduce_rows<<<dim3(1), dim3(1024), 0, stream>>>(row_vals, out);
}

// Round 4
// 190.970 us; speedup vs baseline: 1.0079x; 1.0079x over previous
//
#include <hip/hip_runtime.h>

static constexpr int N = 4096;
static constexpr int D = 8192;
static constexpr int BLOCK = 256;   // 4 waves/block

// Kernel 1: quarter-row per wave, 16384 waves total, no barriers/LDS.
//   waveId = blockIdx*4+wave; row = waveId>>2; q = waveId&3
//   q=0,1 : masked phase, cols [q*2048,(q+1)*2048)  -> denom,ssum,fcnt partials
//   q=2,3 : denom-only,  cols [4096+(q-2)*2048, ...)
// Self-pair (j==row) is NOT excluded here; combine kernel subtracts
// A[i,i], exp(A[i,i]/10), and 1 analytically (self always label-matches).
__global__ __launch_bounds__(BLOCK) void supcon_partial(
    const float* __restrict__ emb,
    const int* __restrict__ labels,
    float4* __restrict__ wsA,          // [N*2] {denom, ssum, fcnt, 0}
    float* __restrict__ wsB)           // [N*2] denom
{
    const int wave = threadIdx.x >> 6;
    const int lane = threadIdx.x & 63;
    const int waveId = blockIdx.x * 4 + wave;
    const int row = waveId >> 2;
    const int q   = waveId & 3;

    const float4* rowp = reinterpret_cast<const float4*>(emb + (size_t)row * D);

    if (q < 2) {
        // masked quarter: 512 float4 over 64 lanes = 8 f4/lane (+8 i4 labels)
        const int lab_i = labels[row];                 // wave-uniform
        const int4* labp = reinterpret_cast<const int4*>(labels);
        float4 v[8]; int4 lj[8];
        #pragma unroll
        for (int i = 0; i < 8; ++i) {
            const int idx = q * 512 + i * 64 + lane;
            v[i]  = rowp[idx];
            lj[i] = labp[idx];                          // 8 KB slice, L1-hot
        }
        float denom = 0.f, ssum = 0.f, fcnt = 0.f;
        #pragma unroll
        for (int i = 0; i < 8; ++i) {
            const float xs[4] = {v[i].x, v[i].y, v[i].z, v[i].w};
            const int   ls[4] = {lj[i].x, lj[i].y, lj[i].z, lj[i].w};
            #pragma unroll
            for (int k = 0; k < 4; ++k) {
                float a = __expf(xs[k] * xs[k] * 0.1f);
                denom += a;
                float b = __expf(a * 0.1f);
                bool m = (ls[k] == lab_i);              // includes self; fixed later
                ssum += m ? b : 0.f;
                fcnt += m ? 1.f : 0.f;
            }
        }
        #pragma unroll
        for (int off = 32; off > 0; off >>= 1) {
            denom += __shfl_down(denom, off);
            ssum  += __shfl_down(ssum,  off);
            fcnt  += __shfl_down(fcnt,  off);
        }
        if (lane == 0)
            wsA[row * 2 + q] = make_float4(denom, ssum, fcnt, 0.f);
    } else {
        // denom-only quarter
        float4 v[8];
        #pragma unroll
        for (int i = 0; i < 8; ++i)
            v[i] = rowp[1024 + (q - 2) * 512 + i * 64 + lane];
        float denom = 0.f;
        #pragma unroll
        for (int i = 0; i < 8; ++i) {
            denom += __expf(v[i].x * v[i].x * 0.1f);
            denom += __expf(v[i].y * v[i].y * 0.1f);
            denom += __expf(v[i].z * v[i].z * 0.1f);
            denom += __expf(v[i].w * v[i].w * 0.1f);
        }
        #pragma unroll
        for (int off = 32; off > 0; off >>= 1)
            denom += __shfl_down(denom, off);
        if (lane == 0)
            wsB[row * 2 + (q - 2)] = denom;
    }
}

// Kernel 2: one thread per row -> per-row log expr -> block reduce -> atomic
__global__ __launch_bounds__(256) void supcon_combine(
    const float* __restrict__ emb,
    const float4* __restrict__ wsA,
    const float* __restrict__ wsB,
    float* __restrict__ out)
{
    const int row = blockIdx.x * 256 + threadIdx.x;
    const float4 p0 = wsA[row * 2 + 0];
    const float4 p1 = wsA[row * 2 + 1];
    const float b0 = wsB[row * 2 + 0];
    const float b1 = wsB[row * 2 + 1];
    const float x  = emb[(size_t)row * D + row];        // diagonal element
    const float ad = __expf(x * x * 0.1f);              // A[i,i]

    const float denom = (p0.x + p1.x + b0 + b1) - ad;
    const float ssum  = (p0.y + p1.y) - __expf(ad * 0.1f);
    const float fcnt  = (p0.z + p1.z) - 1.f;
    float val = __logf(ssum) - __logf(denom) - __logf(fcnt);

    #pragma unroll
    for (int off = 32; off > 0; off >>= 1)
        val += __shfl_down(val, off);
    __shared__ float sb[4];
    if ((threadIdx.x & 63) == 0) sb[threadIdx.x >> 6] = val;
    __syncthreads();
    if (threadIdx.x == 0)
        atomicAdd(out, sb[0] + sb[1] + sb[2] + sb[3]);
}

extern "C" void kernel_launch(void* const* d_in, const int* in_sizes, int n_in,
                              void* d_out, int out_size, void* d_ws, size_t ws_size,
                              hipStream_t stream) {
    const float* emb  = (const float*)d_in[0];
    const int* labels = (const int*)d_in[1];
    float* out        = (float*)d_out;

    float4* wsA = (float4*)d_ws;                        // 128 KB
    float*  wsB = (float*)((char*)d_ws + N * 2 * sizeof(float4));  // 32 KB

    hipMemsetAsync(out, 0, sizeof(float), stream);      // d_out is poisoned pre-launch
    supcon_partial<<<dim3(N * 4 / 4), dim3(BLOCK), 0, stream>>>(emb, labels, wsA, wsB);
    supcon_combine<<<dim3(N / 256), dim3(256), 0, stream>>>(emb, wsA, wsB, out);
}

// Round 5
// 188.020 us; speedup vs baseline: 1.0237x; 1.0157x over previous
//
#include <hip/hip_runtime.h>

static constexpr int N = 4096;
static constexpr int D = 8192;
static constexpr int BLOCK = 256;   // 4 waves/block

// Quarter-row per wave, 16384 waves, no barriers/LDS in the hot kernel.
//   waveId = blockIdx*4+wave; row = waveId>>2; q = waveId&3
//   q=0,1 : masked phase, cols [q*2048,(q+1)*2048) -> {denom, ssum, fcnt, diag}
//   q=2,3 : denom-only,  cols [4096+(q-2)*2048, ...)
// Self-pair kept in ssum/fcnt; combine subtracts exp(diag/10) and 1.
// sched_barrier(0) pins all global loads BEFORE any compute: without it the
// scheduler sinks loads to their uses (R1 profile: VGPR_Count=12 with 8
// float4 "in flight" -> MLP collapsed to ~1, kernel latency-bound).
__global__ __launch_bounds__(BLOCK) void supcon_partial(
    const float* __restrict__ emb,
    const int* __restrict__ labels,
    float4* __restrict__ wsA,          // [N*2] {denom, ssum, fcnt, diag}
    float* __restrict__ wsB)           // [N*2] denom
{
    const int wave = threadIdx.x >> 6;
    const int lane = threadIdx.x & 63;
    const int waveId = blockIdx.x * 4 + wave;
    const int row = waveId >> 2;
    const int q   = waveId & 3;

    const float4* rowp = reinterpret_cast<const float4*>(emb + (size_t)row * D);

    if (q < 2) {
        const int lab_i = labels[row];                  // wave-uniform
        const int4* labp = reinterpret_cast<const int4*>(labels);
        float4 v[8]; int4 lj[8];
        #pragma unroll
        for (int i = 0; i < 8; ++i) {
            const int idx = q * 512 + i * 64 + lane;
            v[i]  = rowp[idx];
            lj[i] = labp[idx];
        }
        __builtin_amdgcn_sched_barrier(0);              // 16 loads stay in flight
        float denom = 0.f, ssum = 0.f, fcnt = 0.f, diag = 0.f;
        #pragma unroll
        for (int i = 0; i < 8; ++i) {
            const int j0 = (q * 512 + i * 64 + lane) * 4;
            const float xs[4] = {v[i].x, v[i].y, v[i].z, v[i].w};
            const int   ls[4] = {lj[i].x, lj[i].y, lj[i].z, lj[i].w};
            #pragma unroll
            for (int k = 0; k < 4; ++k) {
                float a = __expf(xs[k] * xs[k] * 0.1f);
                denom += a;
                float b = __expf(a * 0.1f);
                bool m = (ls[k] == lab_i);              // includes self; fixed in combine
                ssum += m ? b : 0.f;
                fcnt += m ? 1.f : 0.f;
                diag += (j0 + k == row) ? a : 0.f;      // at most one lane nonzero
            }
        }
        #pragma unroll
        for (int off = 32; off > 0; off >>= 1) {
            denom += __shfl_down(denom, off);
            ssum  += __shfl_down(ssum,  off);
            fcnt  += __shfl_down(fcnt,  off);
            diag  += __shfl_down(diag,  off);
        }
        if (lane == 0)
            wsA[row * 2 + q] = make_float4(denom, ssum, fcnt, diag);
    } else {
        float4 v[8];
        #pragma unroll
        for (int i = 0; i < 8; ++i)
            v[i] = rowp[1024 + (q - 2) * 512 + i * 64 + lane];
        __builtin_amdgcn_sched_barrier(0);              // 8 loads stay in flight
        float denom = 0.f;
        #pragma unroll
        for (int i = 0; i < 8; ++i) {
            denom += __expf(v[i].x * v[i].x * 0.1f);
            denom += __expf(v[i].y * v[i].y * 0.1f);
            denom += __expf(v[i].z * v[i].z * 0.1f);
            denom += __expf(v[i].w * v[i].w * 0.1f);
        }
        #pragma unroll
        for (int off = 32; off > 0; off >>= 1)
            denom += __shfl_down(denom, off);
        if (lane == 0)
            wsB[row * 2 + (q - 2)] = denom;
    }
}

// One thread per row: per-row log expr -> block reduce -> atomic (16 blocks).
__global__ __launch_bounds__(256) void supcon_combine(
    const float4* __restrict__ wsA,
    const float* __restrict__ wsB,
    float* __restrict__ out)
{
    const int row = blockIdx.x * 256 + threadIdx.x;
    const float4 p0 = wsA[row * 2 + 0];
    const float4 p1 = wsA[row * 2 + 1];
    const float b0 = wsB[row * 2 + 0];
    const float b1 = wsB[row * 2 + 1];
    const float ad = p0.w + p1.w;                       // A[i,i] (one quarter nonzero)

    const float denom = (p0.x + p1.x + b0 + b1) - ad;
    const float ssum  = (p0.y + p1.y) - __expf(ad * 0.1f);
    const float fcnt  = (p0.z + p1.z) - 1.f;
    float val = __logf(ssum) - __logf(denom) - __logf(fcnt);

    #pragma unroll
    for (int off = 32; off > 0; off >>= 1)
        val += __shfl_down(val, off);
    __shared__ float sb[4];
    if ((threadIdx.x & 63) == 0) sb[threadIdx.x >> 6] = val;
    __syncthreads();
    if (threadIdx.x == 0)
        atomicAdd(out, sb[0] + sb[1] + sb[2] + sb[3]);
}

extern "C" void kernel_launch(void* const* d_in, const int* in_sizes, int n_in,
                              void* d_out, int out_size, void* d_ws, size_t ws_size,
                              hipStream_t stream) {
    const float* emb  = (const float*)d_in[0];
    const int* labels = (const int*)d_in[1];
    float* out        = (float*)d_out;

    float4* wsA = (float4*)d_ws;                                   // 128 KB
    float*  wsB = (float*)((char*)d_ws + N * 2 * sizeof(float4));  // 32 KB

    hipMemsetAsync(out, 0, sizeof(float), stream);   // d_out poisoned pre-launch
    supcon_partial<<<dim3(N), dim3(BLOCK), 0, stream>>>(emb, labels, wsA, wsB);
    supcon_combine<<<dim3(N / 256), dim3(256), 0, stream>>>(wsA, wsB, out);
}